// Round 13
// baseline (292.537 us; speedup 1.0000x reference)
//
#include <hip/hip_runtime.h>

#define N 1024
#define D 256
#define NB 1152  // persistent blocks: 4.5/CU, 9 waves/CU (<<32) — co-resident

// Static scratch (R12-verified location) + monotonic barrier counter.
// g_bar never resets: each launch adds exactly NB (one barrier), so it is
// always ==0 (mod NB) at launch entry -> graph-replay safe.
__device__ float4 g_scr[(D / 2) * N];
__device__ int g_bar;

// Fused single-launch kernel. R1-R12 ledger: pair wall ~40us invariant to
// VALU/TLP/traffic/prefetch/layout; fill (42us) is unconditional harness
// re-poison; remaining addressable term = prep + 2 launch gaps (~7-8us).
// Phase A: blocks<1024 prep one row (wave 0, reg-only butterfly norm) ->
//   scr[g][row] = (mu_{2g},mu_{2g+1},sig_{2g},sig_{2g+1}) (verified layout).
// Barrier: monotonic fetch_add + agent-scope acquire spin (G16 device-scope).
// Phase B: each block runs exactly 2 triangular 2x128 tiles (R2-verified
//   body, bit-identical math): tile = b and b+NB.
__global__ __launch_bounds__(128) void fused(
    const float* __restrict__ muX, const float* __restrict__ ls,
    float* __restrict__ out) {
  const int b = blockIdx.x;
  const int t = threadIdx.x;

  // ---- phase A: prep (blocks 0..1023, wave 0 only) ----
  if (b < 1024 && t < 64) {
    const int l = t;  // float4 chunk: d = 4l..4l+3
    const float4 mu = ((const float4*)muX)[b * 64 + l];
    const float4 e = ((const float4*)ls)[b * 64 + l];
    float s =
        fmaf(mu.x, mu.x, fmaf(mu.y, mu.y, fmaf(mu.z, mu.z, mu.w * mu.w)));
#pragma unroll
    for (int m = 32; m >= 1; m >>= 1) s += __shfl_xor(s, m, 64);
    const float rden = 1.0f / fmaxf(sqrtf(s), 1e-12f);  // F.normalize eps
    float4 sg;
    sg.x = __expf(e.x) + 5e-11f; sg.y = __expf(e.y) + 5e-11f;  // eps folded
    sg.z = __expf(e.z) + 5e-11f; sg.w = __expf(e.w) + 5e-11f;
    g_scr[(size_t)(2 * l) * N + b] =
        make_float4(mu.x * rden, mu.y * rden, sg.x, sg.y);
    g_scr[(size_t)(2 * l + 1) * N + b] =
        make_float4(mu.z * rden, mu.w * rden, sg.z, sg.w);
  }

  // ---- monotonic global barrier ----
  __threadfence();  // release: scr stores visible at agent scope
  __syncthreads();
  if (t == 0) {
    const int old = __hip_atomic_fetch_add(&g_bar, 1, __ATOMIC_ACQ_REL,
                                           __HIP_MEMORY_SCOPE_AGENT);
    const int target = (old / NB + 1) * NB;
    while (__hip_atomic_load(&g_bar, __ATOMIC_ACQUIRE,
                             __HIP_MEMORY_SCOPE_AGENT) < target) {
      __builtin_amdgcn_s_sleep(1);
    }
  }
  __syncthreads();
  __threadfence();  // acquire side for all threads in the block

  const float4* __restrict__ msT4 = (const float4*)g_scr;

  // ---- phase B: two pair tiles per block (R2-verified body) ----
  for (int tile = b; tile < 64 * (8 * 9 / 2); tile += NB) {
    int L = tile;
    int js = 0, base = 0;  // slab js has 64*(js+1) row-tiles of 2 rows
    while (L >= base + 64 * (js + 1)) { base += 64 * (js + 1); ++js; }
    const int ib = L - base;
    const int j0 = js * 128, i0 = ib * 2;
    const bool diag = (ib >= js * 64);  // tile straddles the diagonal
    const int j = j0 + t;

    float acc[2] = {0.f, 0.f};
    float p[2] = {1.f, 1.f};
    int ea[2] = {0, 0};

#pragma unroll 4
    for (int gg = 0; gg < D / 4; ++gg) {  // 4 d's per iteration
      const float4 jva = msT4[(size_t)(2 * gg) * N + j];
      const float4 jvb = msT4[(size_t)(2 * gg + 1) * N + j];
#pragma unroll
      for (int k = 0; k < 2; ++k) {
        const float4 iva = msT4[(size_t)(2 * gg) * N + i0 + k];      // SGPR
        const float4 ivb = msT4[(size_t)(2 * gg + 1) * N + i0 + k];  // SGPR
        const float sa0 = iva.z + jva.z, sa1 = iva.w + jva.w;
        const float da0 = iva.x - jva.x, da1 = iva.y - jva.y;
        const float sb0 = ivb.z + jvb.z, sb1 = ivb.w + jvb.w;
        const float db0 = ivb.x - jvb.x, db1 = ivb.y - jvb.y;
        const float qa0 = da0 * da0, qa1 = da1 * da1;
        const float qb0 = db0 * db0, qb1 = db1 * db1;
        const float s01 = sa0 * sa1, s23 = sb0 * sb1;
        float na = qa0 * sa1; na = fmaf(qa1, sa0, na);
        float nb = qb0 * sb1; nb = fmaf(qb1, sb0, nb);
        float num = na * s23; num = fmaf(nb, s01, num);
        const float den = s01 * s23;
        acc[k] = fmaf(num, __builtin_amdgcn_rcpf(den), acc[k]);
        p[k] *= den;
      }
      if (gg & 1) {  // strip every 8 d's: exponent safe
#pragma unroll
        for (int k = 0; k < 2; ++k) {
          const int bb = __float_as_int(p[k]);
          ea[k] += bb >> 23;
          p[k] = __int_as_float((bb & 0x007fffff) | 0x3f800000);
        }
      }
    }

    constexpr float LN2 = 0.6931471805599453f;
    float v[2];
#pragma unroll
    for (int k = 0; k < 2; ++k) {
      const float lg2 = (float)(ea[k] - 127 * (D / 8)) + __log2f(p[k]);
      v[k] = -(acc[k] + LN2 * lg2);
    }

    if (!diag) {  // strictly-upper tile: unmasked direct + mirror writes
      out[(size_t)i0 * N + j] = v[0];
      out[(size_t)(i0 + 1) * N + j] = v[1];
      *(float2*)(out + (size_t)j * N + i0) = make_float2(v[0], v[1]);
    } else {  // diagonal tile: per-element masks
#pragma unroll
      for (int k = 0; k < 2; ++k) {
        const int i = i0 + k;
        if (j >= i) out[(size_t)i * N + j] = v[k];
        if (j > i) out[(size_t)j * N + i] = v[k];
      }
    }
  }
}

extern "C" void kernel_launch(void* const* d_in, const int* in_sizes, int n_in,
                              void* d_out, int out_size, void* d_ws, size_t ws_size,
                              hipStream_t stream) {
  const float* muX = (const float*)d_in[0];
  const float* ls  = (const float*)d_in[1];
  float* out = (float*)d_out;
  (void)d_ws; (void)ws_size;  // workspace unused (R12: fill is unconditional)
  fused<<<dim3(NB), dim3(128), 0, stream>>>(muX, ls, out);
}

// Round 14
// 89.920 us; speedup vs baseline: 3.2533x; 3.2533x over previous
//
#include <hip/hip_runtime.h>

#define N 1024
#define D 256

// ---------------- prep ----------------
// Reg-only wave-per-row prep (R13-phase-A math, field-verified): 256 blocks
// x 256 thr = full GPU (old prep3: 128 blocks = half idle, 3 barriers, LDS
// round-trips, 8-pass write loop). Wave w preps row blockIdx*4+w: coalesced
// float4 loads, 64-lane butterfly norm, exp, direct transposed stores.
// scr layout (= R2-R10 msT4): scr[g][row] = (mu_{2g},mu_{2g+1},sig_{2g},sig_{2g+1}).
__global__ __launch_bounds__(256) void prep_fast(
    const float* __restrict__ muX, const float* __restrict__ ls,
    float4* __restrict__ scr) {
  const int t = threadIdx.x;
  const int w = t >> 6, l = t & 63;  // wave -> row, lane -> float4 chunk
  const int row = blockIdx.x * 4 + w;
  const float4 mu = ((const float4*)muX)[(size_t)row * 64 + l];
  const float4 e = ((const float4*)ls)[(size_t)row * 64 + l];
  float s =
      fmaf(mu.x, mu.x, fmaf(mu.y, mu.y, fmaf(mu.z, mu.z, mu.w * mu.w)));
#pragma unroll
  for (int m = 32; m >= 1; m >>= 1) s += __shfl_xor(s, m, 64);
  const float rden = 1.0f / fmaxf(sqrtf(s), 1e-12f);  // F.normalize eps
  float4 sg;
  sg.x = __expf(e.x) + 5e-11f; sg.y = __expf(e.y) + 5e-11f;  // eps folded
  sg.z = __expf(e.z) + 5e-11f; sg.w = __expf(e.w) + 5e-11f;
  // chunk l covers d=4l..4l+3 -> g rows 2l (d0,d1) and 2l+1 (d2,d3)
  scr[(size_t)(2 * l) * N + row] =
      make_float4(mu.x * rden, mu.y * rden, sg.x, sg.y);
  scr[(size_t)(2 * l + 1) * N + row] =
      make_float4(mu.z * rden, mu.w * rden, sg.z, sg.w);
}

// ---------------- pair ----------------
// R10-verified VERBATIM: triangular 2x128 tiles, D-split 4 waves (256 thr),
// h pinned to SGPR via readfirstlane so i-side reads stay s_load.
// The ~40us pair wall is invariant to VALU count, clean TLP x2, traffic
// x0.5, prefetch, 3 i-side mechanisms, and loop rotation (R1-R13 ledger) —
// structurally floored; left untouched.
__global__ __launch_bounds__(256) void pair_kernel(
    const float4* __restrict__ msT4, float* __restrict__ out) {
  int L = blockIdx.x;
  int js = 0, base = 0;  // slab js has 64*(js+1) row-tiles of 2 rows
  while (L >= base + 64 * (js + 1)) { base += 64 * (js + 1); ++js; }
  const int ib = L - base;
  const int j0 = js * 128, i0 = ib * 2;
  const bool diag = (ib >= js * 64);  // tile straddles the diagonal
  const int t = threadIdx.x;
  const int lane = t & 127;
  const int h = __builtin_amdgcn_readfirstlane(t >> 7);  // SGPR D-half id
  const int j = j0 + lane;

  float acc[2] = {0.f, 0.f};
  float p[2] = {1.f, 1.f};
  int ea[2] = {0, 0};

#pragma unroll 4
  for (int it = 0; it < 32; ++it) {  // 32 x 4 d's per half
    const int gg = h * 32 + it;      // SGPR + loop counter -> SALU
    const float4 jva = msT4[(size_t)(2 * gg) * N + j];
    const float4 jvb = msT4[(size_t)(2 * gg + 1) * N + j];
#pragma unroll
    for (int k = 0; k < 2; ++k) {
      const float4 iva = msT4[(size_t)(2 * gg) * N + i0 + k];      // s_load
      const float4 ivb = msT4[(size_t)(2 * gg + 1) * N + i0 + k];  // s_load
      const float sa0 = iva.z + jva.z, sa1 = iva.w + jva.w;
      const float da0 = iva.x - jva.x, da1 = iva.y - jva.y;
      const float sb0 = ivb.z + jvb.z, sb1 = ivb.w + jvb.w;
      const float db0 = ivb.x - jvb.x, db1 = ivb.y - jvb.y;
      const float qa0 = da0 * da0, qa1 = da1 * da1;
      const float qb0 = db0 * db0, qb1 = db1 * db1;
      const float s01 = sa0 * sa1, s23 = sb0 * sb1;
      float na = qa0 * sa1; na = fmaf(qa1, sa0, na);
      float nb = qb0 * sb1; nb = fmaf(qb1, sb0, nb);
      float num = na * s23; num = fmaf(nb, s01, num);
      const float den = s01 * s23;
      acc[k] = fmaf(num, __builtin_amdgcn_rcpf(den), acc[k]);
      p[k] *= den;
    }
    if (it & 1) {  // strip every 8 d's: 16 strips per half, exponent safe
#pragma unroll
      for (int k = 0; k < 2; ++k) {
        const int bb = __float_as_int(p[k]);
        ea[k] += bb >> 23;
        p[k] = __int_as_float((bb & 0x007fffff) | 0x3f800000);
      }
    }
  }

  constexpr float LN2 = 0.6931471805599453f;
  float part[2];
#pragma unroll
  for (int k = 0; k < 2; ++k) {
    const float lg2 = (float)(ea[k] - 127 * 16) + __log2f(p[k]);
    part[k] = acc[k] + LN2 * lg2;  // this half's additive contribution
  }

  __shared__ float sP[2][128];
  if (h) {
    sP[0][lane] = part[0];
    sP[1][lane] = part[1];
  }
  __syncthreads();
  if (!h) {
    float v[2];
    v[0] = -(part[0] + sP[0][lane]);
    v[1] = -(part[1] + sP[1][lane]);
    if (!diag) {  // strictly-upper tile: unmasked direct + mirror writes
      out[(size_t)i0 * N + j] = v[0];
      out[(size_t)(i0 + 1) * N + j] = v[1];
      *(float2*)(out + (size_t)j * N + i0) = make_float2(v[0], v[1]);
    } else {  // diagonal tile: per-element masks
#pragma unroll
      for (int k = 0; k < 2; ++k) {
        const int i = i0 + k;
        if (j >= i) out[(size_t)i * N + j] = v[k];
        if (j > i) out[(size_t)j * N + i] = v[k];
      }
    }
  }
}

extern "C" void kernel_launch(void* const* d_in, const int* in_sizes, int n_in,
                              void* d_out, int out_size, void* d_ws, size_t ws_size,
                              hipStream_t stream) {
  const float* muX = (const float*)d_in[0];
  const float* ls  = (const float*)d_in[1];
  float* out = (float*)d_out;
  float4* scr = (float4*)d_ws;  // 2 MB transposed (mu,sig) layout
  prep_fast<<<dim3(N / 4), dim3(256), 0, stream>>>(muX, ls, scr);
  const int nblocks = 64 * (8 * 9 / 2);  // 2304 triangular 2x128 tiles
  pair_kernel<<<dim3(nblocks), dim3(256), 0, stream>>>((const float4*)scr,
                                                       out);
}